// Round 9
// baseline (148.374 us; speedup 1.0000x reference)
//
#include <hip/hip_runtime.h>
#include <stdint.h>

#define N_TOK 4096
#define DIM   512
#define BATCH 4
#define BN    (BATCH * N_TOK)
#define NSUP  16                      // 256-row super-tiles per batch
#define IPW   64                      // i-rows per wave (A resident in regs)
#define IPB   256                     // i-rows per block (4 waves) = one super-tile
#define CHUNK 17                      // j-group instances per block (2176 = 128*17)
#define NSLOT 31                      // 16 i-side chunk slots + 15 j-side row slots

typedef __attribute__((ext_vector_type(4))) float f32x4;
typedef __attribute__((ext_vector_type(8))) int   i32x8;

typedef const __attribute__((address_space(1))) uint32_t* gptr_t;
typedef __attribute__((address_space(3))) uint32_t* lptr_t;

__device__ __forceinline__ float sumsq8(uint lo, uint hi) {
    float s = 0.f, f;
    f = __builtin_amdgcn_cvt_f32_fp8((int)lo, 0); s = fmaf(f, f, s);
    f = __builtin_amdgcn_cvt_f32_fp8((int)lo, 1); s = fmaf(f, f, s);
    f = __builtin_amdgcn_cvt_f32_fp8((int)lo, 2); s = fmaf(f, f, s);
    f = __builtin_amdgcn_cvt_f32_fp8((int)lo, 3); s = fmaf(f, f, s);
    f = __builtin_amdgcn_cvt_f32_fp8((int)hi, 0); s = fmaf(f, f, s);
    f = __builtin_amdgcn_cvt_f32_fp8((int)hi, 1); s = fmaf(f, f, s);
    f = __builtin_amdgcn_cvt_f32_fp8((int)hi, 2); s = fmaf(f, f, s);
    f = __builtin_amdgcn_cvt_f32_fp8((int)hi, 3); s = fmaf(f, f, s);
    return s;
}

// ---------- prep: fp8 convert -> fbT (operand-image layout) + per-row quantized
// sumsq + zero-init of the 31 partial slots (sparsely written by entropy).
__global__ __launch_bounds__(256) void prep_kernel(
    const float* __restrict__ feat, uint8_t* __restrict__ fbT,
    float* __restrict__ sq, float* __restrict__ Sp, float* __restrict__ Tp)
{
    __shared__ __align__(16) long lt[1024];        // [chunk c 0..63][row16], swizzled
    const int t = threadIdx.x;
    const int row16 = t >> 4, seg = t & 15;
    const size_t grp = blockIdx.x;
    const size_t row = grp * 16 + row16;

    // zero partial slots: 31*BN floats per array = 126976 float4 each
    {
        size_t idx = grp * 256 + t;
        if (idx < (size_t)NSLOT * BN / 4) {
            float4 z = {0.f, 0.f, 0.f, 0.f};
            ((float4*)Sp)[idx] = z;
            ((float4*)Tp)[idx] = z;
        }
    }

    const float4* src = (const float4*)(feat + row * DIM + seg * 32);
    uint32_t wd[8];
    float s = 0.f;
#pragma unroll
    for (int i = 0; i < 4; ++i) {
        float4 a = src[2 * i], b = src[2 * i + 1];
        uint lo = (uint)__builtin_amdgcn_cvt_pk_fp8_f32(a.x, a.y, 0, false);
        lo      = (uint)__builtin_amdgcn_cvt_pk_fp8_f32(a.z, a.w, (int)lo, true);
        uint hi = (uint)__builtin_amdgcn_cvt_pk_fp8_f32(b.x, b.y, 0, false);
        hi      = (uint)__builtin_amdgcn_cvt_pk_fp8_f32(b.z, b.w, (int)hi, true);
        wd[2 * i] = lo; wd[2 * i + 1] = hi;
        s += sumsq8(lo, hi);
    }

#pragma unroll
    for (int i = 0; i < 4; ++i) {
        int c = seg * 4 + i;                       // 8B chunk of this row
        long d = ((long)(unsigned)wd[2 * i + 1] << 32) | (unsigned)wd[2 * i];
        lt[c * 16 + ((row16 + c) & 15)] = d;
    }

#pragma unroll
    for (int m = 1; m < 16; m <<= 1) s += __shfl_xor(s, m);
    if (seg == 0) sq[row] = s;

    __syncthreads();
    long* ot = (long*)(fbT + grp * 8192);
#pragma unroll
    for (int i = 0; i < 4; ++i) {
        int p    = t + i * 256;                    // output long index, coalesced
        int kk   = p >> 8;
        int rem  = p & 255;
        int half = rem >> 7;
        int l6   = (rem >> 1) & 63;
        int qq   = l6 >> 4;
        int r    = l6 & 15;
        int w8   = half * 2 + (p & 1);
        int c    = kk * 16 + qq * 4 + w8;
        ot[p] = lt[c * 16 + ((r + c) & 15)];
    }
}

// ---------- entropy: symmetry-halved, PERFECTLY PACKED. R8 lesson: per-block
// fixed cost (A-prologue + ramp) is large — keep block count at 512 (= exact
// co-residency capacity) with R7-sized bodies. Per batch the triangle holds
// 2176 = 128*17 j-group instances; block m owns groups [17m, 17m+17) of the
// row-major walk (row a covers supers b>=a). A chunk crosses at most ONE row
// boundary -> <=2 segments, each with its own A-prologue (~12% of blocks).
// Odd group counts: dummy group (pj=-1e30 -> early-out always skips, exact 0).
// Exactly-once slots, atomic-free, zero-initialized by prep:
//   i-side of segment (a, chunk): rows of a, slot = mb - C(a)/17 in [0,16)
//   j-side: rows of the chunk's j-range, slot 16+a (skip groups inside super a
//   — within-super sums are complete on the i-side)
// Ledger per segment: stage_sp = 4 loads; prologue stages min(2,NSP) phases;
// phase sp waits vmcnt(4) if sp+2<=NSP else vmcnt(0); stage(sp+2) after seal.
__global__ __launch_bounds__(256, 2) void entropy_kernel(
    const uint8_t* __restrict__ fbT,
    const float* __restrict__ sq, const float* __restrict__ temp,
    float* __restrict__ Sp, float* __restrict__ Tp)
{
    __shared__ uint4 buf[2][1024];                 // 2 x 16KB (2 groups x 8KB)
    __shared__ float sqlds[288];                   // segment j-slice sq
    __shared__ float sjS[4][288];                  // per-wave j-side partials
    __shared__ float sjT[4][288];
    const int t    = threadIdx.x;
    const int w    = t >> 6;
    const int lane = t & 63;
    const int q    = lane >> 4;
    const int c16  = lane & 15;
    const int lbo  = lane * 16;

    const int mb    = blockIdx.x & 127;
    const int batch = blockIdx.x >> 7;
    const size_t rowbase = (size_t)batch * N_TOK;

    const float tau    = temp[0];
    const float inv2t2 = 0.5f / (tau * tau);
    const float cg_    = 1.0f / (tau * tau);

    // locate first segment: row a of the triangle walk, offset o within row
    const int g0 = mb * CHUNK;
    int a = 0, Ca = 0;
    while (Ca + 16 * (NSUP - a) <= g0) { Ca += 16 * (NSUP - a); ++a; }
    const int o      = g0 - Ca;
    const int rowlen = 16 * (NSUP - a);
    const int n1     = (rowlen - o < CHUNK) ? (rowlen - o) : CHUNK;

    auto run_seg = [&](int aa, int CaX, int jjstart, int n) {
        const int slot_i = mb - CaX / CHUNK;       // chunk ordinal within row aa
        const int iw = aa * IPB + w * IPW;

        // ---- per-segment prologue ----
        i32x8 afrag[4][4];
#pragma unroll
        for (int s = 0; s < 4; ++s) {
            const uint8_t* ga = fbT + ((rowbase + iw) / 16 + s) * 8192;
#pragma unroll
            for (int kk = 0; kk < 4; ++kk) {
                uint4 lo = *(const uint4*)(ga + kk * 2048 + lbo);
                uint4 hi = *(const uint4*)(ga + kk * 2048 + 1024 + lbo);
                i32x8 v = {(int)lo.x, (int)lo.y, (int)lo.z, (int)lo.w,
                           (int)hi.x, (int)hi.y, (int)hi.z, (int)hi.w};
                afrag[s][kk] = v;
            }
        }
        float pi_[4][4];
        float pim = -1e30f;
#pragma unroll
        for (int s = 0; s < 4; ++s) {
            float4 p4 = *(const float4*)(sq + rowbase + iw + s * 16 + q * 4);
            pi_[s][0] = -p4.x * inv2t2; pi_[s][1] = -p4.y * inv2t2;
            pi_[s][2] = -p4.z * inv2t2; pi_[s][3] = -p4.w * inv2t2;
            pim = fmaxf(pim, fmaxf(fmaxf(pi_[s][0], pi_[s][1]),
                                   fmaxf(pi_[s][2], pi_[s][3])));
        }
        for (int idx = t; idx < n * 16; idx += 256)
            sqlds[idx] = sq[rowbase + (size_t)jjstart * 16 + idx];
        for (int idx = lane; idx < n * 16; idx += 64) {
            sjS[w][idx] = 0.f; sjT[w][idx] = 0.f;
        }

        float S[4][4], T[4][4];
#pragma unroll
        for (int s = 0; s < 4; ++s)
#pragma unroll
            for (int r = 0; r < 4; ++r) { S[s][r] = 0.f; T[s][r] = 0.f; }

        const uint8_t* bgbase = fbT
            + ((size_t)batch * (N_TOK / 16) + (size_t)jjstart) * 8192;
        const int NSPs = (n + 1) / 2;

        auto stage_sp = [&](int sp, int b) {       // wave w: its 2KB of 2 groups
#pragma unroll
            for (int i = 0; i < 2; ++i) {
                int k = 2 * sp + i; if (k > n - 1) k = n - 1;   // dummy re-stage
                const uint8_t* gs = bgbase + (size_t)k * 8192 + w * 2048 + lbo;
                uint8_t* ld = (uint8_t*)(&buf[b][0]) + i * 8192 + w * 2048;
                __builtin_amdgcn_global_load_lds((gptr_t)(const void*)gs,
                                                 (lptr_t)(void*)ld, 16, 0, 0);
                __builtin_amdgcn_global_load_lds((gptr_t)(const void*)(gs + 1024),
                                                 (lptr_t)(void*)(ld + 1024), 16, 0, 0);
            }
        };

        // clean ledger: drain prior stores/afrag, seal sqlds/sj zeros, sync
        asm volatile("s_waitcnt vmcnt(0) lgkmcnt(0)" ::: "memory");
        __builtin_amdgcn_s_barrier();
        stage_sp(0, 0);
        if (NSPs > 1) stage_sp(1, 1);

        for (int sp = 0; sp < NSPs; ++sp) {
            if (sp + 2 <= NSPs) asm volatile("s_waitcnt vmcnt(4)" ::: "memory");
            else                asm volatile("s_waitcnt vmcnt(0)" ::: "memory");
            __builtin_amdgcn_s_barrier();          // all waves' stage(sp) confirmed
            __builtin_amdgcn_sched_barrier(0);

            const uint8_t* sb = (const uint8_t*)(&buf[sp & 1][0]);
            __builtin_amdgcn_s_setprio(1);
#pragma unroll
            for (int i = 0; i < 2; ++i) {          // un-fenced 2-group body
                const int k    = 2 * sp + i;
                const int kr   = (k > n - 1) ? (n - 1) : k;
                const bool dmy = (k > n - 1);
                const uint8_t* bs = sb + i * 8192;
                float pj = dmy ? -1e30f : -sqlds[kr * 16 + c16] * inv2t2;
                f32x4 acc[4] = {{0,0,0,0},{0,0,0,0},{0,0,0,0},{0,0,0,0}};
#pragma unroll
                for (int kk = 0; kk < 4; ++kk) {
                    uint4 lo = *(const uint4*)(bs + kk * 2048 + lbo);
                    uint4 hi = *(const uint4*)(bs + kk * 2048 + 1024 + lbo);
                    i32x8 b = {(int)lo.x, (int)lo.y, (int)lo.z, (int)lo.w,
                               (int)hi.x, (int)hi.y, (int)hi.z, (int)hi.w};
                    acc[0] = __builtin_amdgcn_mfma_scale_f32_16x16x128_f8f6f4(afrag[0][kk], b, acc[0], 0, 0, 0, 127, 0, 127);
                    acc[1] = __builtin_amdgcn_mfma_scale_f32_16x16x128_f8f6f4(afrag[1][kk], b, acc[1], 0, 0, 0, 127, 0, 127);
                    acc[2] = __builtin_amdgcn_mfma_scale_f32_16x16x128_f8f6f4(afrag[2][kk], b, acc[2], 0, 0, 0, 127, 0, 127);
                    acc[3] = __builtin_amdgcn_mfma_scale_f32_16x16x128_f8f6f4(afrag[3][kk], b, acc[3], 0, 0, 0, 127, 0, 127);
                }
                // wave-uniform early-out; skipped groups contribute exp(<=-110)
                // == 0.0f exactly (dummy: pj=-1e30 always skips).
                float m0 = fmaxf(fmaxf(acc[0][0], acc[0][1]), fmaxf(acc[0][2], acc[0][3]));
                float m1 = fmaxf(fmaxf(acc[1][0], acc[1][1]), fmaxf(acc[1][2], acc[1][3]));
                float m2 = fmaxf(fmaxf(acc[2][0], acc[2][1]), fmaxf(acc[2][2], acc[2][3]));
                float m3 = fmaxf(fmaxf(acc[3][0], acc[3][1]), fmaxf(acc[3][2], acc[3][3]));
                float mm = fmaxf(fmaxf(m0, m1), fmaxf(m2, m3));
                float bound = fmaf(mm, cg_, pim + pj);
                if (__any(bound > -110.0f)) {
                    float ks = 0.f, kt = 0.f;
#pragma unroll
                    for (int s = 0; s < 4; ++s)
#pragma unroll
                        for (int r = 0; r < 4; ++r) {
                            float e   = fmaf(acc[s][r], cg_, pi_[s][r] + pj);
                            float ee  = fminf(e, 0.f);
                            float kv  = __expf(ee);
                            float kei = kv * ee;
                            S[s][r] += kv;  T[s][r] += kei;
                            ks      += kv;  kt      += kei;
                        }
                    // j-side: skip groups inside super aa (i-side is complete there)
                    if (((jjstart + kr) >> 4) != aa) {
                        ks += __shfl_xor(ks, 16); ks += __shfl_xor(ks, 32);
                        kt += __shfl_xor(kt, 16); kt += __shfl_xor(kt, 32);
                        if (lane < 16) {
                            sjS[w][kr * 16 + lane] = ks;
                            sjT[w][kr * 16 + lane] = kt;
                        }
                    }
                }
            }
            __builtin_amdgcn_s_setprio(0);

            asm volatile("s_waitcnt lgkmcnt(0)" ::: "memory");
            __builtin_amdgcn_s_barrier();          // all reads of buf sealed
            __builtin_amdgcn_sched_barrier(0);
            if (sp + 2 < NSPs) stage_sp(sp + 2, sp & 1);
        }

        // ---- i-side: reduce over 16 j-columns, write slot slot_i ----
#pragma unroll
        for (int m = 1; m < 16; m <<= 1)
#pragma unroll
            for (int s = 0; s < 4; ++s)
#pragma unroll
                for (int r = 0; r < 4; ++r) {
                    S[s][r] += __shfl_xor(S[s][r], m);
                    T[s][r] += __shfl_xor(T[s][r], m);
                }
        if (c16 == 0) {
#pragma unroll
            for (int s = 0; s < 4; ++s)
#pragma unroll
                for (int r = 0; r < 4; ++r) {
                    size_t idx = (size_t)slot_i * BN + rowbase + iw + s * 16 + q * 4 + r;
                    Sp[idx] = S[s][r];
                    Tp[idx] = T[s][r];
                }
        }

        // ---- j-side: combine 4 waves' partials, write slot 16+aa ----
        __syncthreads();
        for (int idx = t; idx < n * 16; idx += 256) {
            int k = idx >> 4;
            if (((jjstart + k) >> 4) != aa) {
                float s4 = sjS[0][idx] + sjS[1][idx] + sjS[2][idx] + sjS[3][idx];
                float t4 = sjT[0][idx] + sjT[1][idx] + sjT[2][idx] + sjT[3][idx];
                size_t row = rowbase + (size_t)jjstart * 16 + idx;
                Sp[(size_t)(16 + aa) * BN + row] = s4;
                Tp[(size_t)(16 + aa) * BN + row] = t4;
            }
        }
        __syncthreads();                           // sj reads done before next seg
    };

    run_seg(a, Ca, a * 16 + o, n1);
    if (n1 < CHUNK) run_seg(a + 1, Ca + rowlen, (a + 1) * 16, CHUNK - n1);
}

// ---------- finalize: combine 31 partial slots, entropy -> sigmoid -> scale ----------
__global__ __launch_bounds__(256) void finalize_kernel(
    const float* __restrict__ feat, const float* __restrict__ Sp,
    const float* __restrict__ Tp, const float* __restrict__ tgt,
    const float* __restrict__ temp, float* __restrict__ out)
{
    int row  = (blockIdx.x << 2) + (threadIdx.x >> 6);   // global row 0..BN-1
    int lane = threadIdx.x & 63;
    float S = 0.0f, T = 0.0f;
#pragma unroll
    for (int j = 0; j < NSLOT; ++j) {
        S += Sp[(size_t)j * BN + row];
        T += Tp[(size_t)j * BN + row];
    }
    float tau = temp[0];
    float E  = __logf(S) - T / S;                  // entropy (sans +1e-6, bias<4e-3)
    float cs = 1.0f / (1.0f + __expf((E - tgt[0]) / tau));

    const float4* F4 = (const float4*)(feat + (size_t)row * DIM);
    float4*       O4 = (float4*)(out + (size_t)row * DIM);
    float4 v0 = F4[lane], v1 = F4[lane + 64];
    v0.x *= cs; v0.y *= cs; v0.z *= cs; v0.w *= cs;
    v1.x *= cs; v1.y *= cs; v1.z *= cs; v1.w *= cs;
    O4[lane] = v0; O4[lane + 64] = v1;
    if (lane == 0) out[(size_t)BN * DIM + row] = cs;
}

extern "C" void kernel_launch(void* const* d_in, const int* in_sizes, int n_in,
                              void* d_out, int out_size, void* d_ws, size_t ws_size,
                              hipStream_t stream) {
    const float* feat = (const float*)d_in[0];
    const float* tgt  = (const float*)d_in[7];   // target_entropy
    const float* temp = (const float*)d_in[8];   // temperature
    float* out = (float*)d_out;

    char* ws = (char*)d_ws;
    uint8_t* fbT = (uint8_t*)ws;                               // fp8 operand-image, 8.4MB
    float*   sq  = (float*)(fbT + (size_t)BN * DIM);           // quantized row sumsq
    float*   Sp  = sq + BN;                                    // partial S, NSLOT slots
    float*   Tp  = Sp + (size_t)NSLOT * BN;                    // partial T, NSLOT slots

    prep_kernel<<<dim3(BN / 16), dim3(256), 0, stream>>>(feat, fbT, sq, Sp, Tp);
    entropy_kernel<<<dim3(BATCH * 128), dim3(256), 0, stream>>>(fbT, sq, temp, Sp, Tp);
    finalize_kernel<<<dim3(BN / 4), dim3(256), 0, stream>>>(feat, Sp, Tp, tgt, temp, out);
}

// Round 10
// 139.502 us; speedup vs baseline: 1.0636x; 1.0636x over previous
//
#include <hip/hip_runtime.h>
#include <stdint.h>

#define N_TOK 4096
#define DIM   512
#define BATCH 4
#define BN    (BATCH * N_TOK)
#define NSUP  16                      // 256-row super-tiles per batch
#define NPAIR 136                     // NSUP*(NSUP+1)/2 unordered pairs
#define IPW   64                      // i-rows per wave (A resident in regs)
#define IPB   256                     // i-rows per block (4 waves) = one super-tile
#define NG2   16                      // j-groups of 16 per super-tile
#define SPG   4                       // j-groups per superphase (un-fenced body)
#define NSP   (NG2 / SPG)             // 4 superphases

typedef __attribute__((ext_vector_type(4))) float f32x4;
typedef __attribute__((ext_vector_type(8))) int   i32x8;

typedef const __attribute__((address_space(1))) uint32_t* gptr_t;
typedef __attribute__((address_space(3))) uint32_t* lptr_t;

__device__ __forceinline__ float sumsq8(uint lo, uint hi) {
    float s = 0.f, f;
    f = __builtin_amdgcn_cvt_f32_fp8((int)lo, 0); s = fmaf(f, f, s);
    f = __builtin_amdgcn_cvt_f32_fp8((int)lo, 1); s = fmaf(f, f, s);
    f = __builtin_amdgcn_cvt_f32_fp8((int)lo, 2); s = fmaf(f, f, s);
    f = __builtin_amdgcn_cvt_f32_fp8((int)lo, 3); s = fmaf(f, f, s);
    f = __builtin_amdgcn_cvt_f32_fp8((int)hi, 0); s = fmaf(f, f, s);
    f = __builtin_amdgcn_cvt_f32_fp8((int)hi, 1); s = fmaf(f, f, s);
    f = __builtin_amdgcn_cvt_f32_fp8((int)hi, 2); s = fmaf(f, f, s);
    f = __builtin_amdgcn_cvt_f32_fp8((int)hi, 3); s = fmaf(f, f, s);
    return s;
}

// ---------- prep: fp8 convert -> fbT (operand-image layout; A and B per-lane MFMA
// layouts are identical for 16x16x128, so entropy reads BOTH operands from fbT)
// + per-row sumsq of QUANTIZED values (diag d_ii ~ 0 matches ref k_ii=1).
// fbT per 16-row group (8KB):
//   byte = kk*2048 + half*1024 + lane*16 + w8p*8, lane = q*16 + r
//   content = row r, K bytes [kk*128 + q*32 + (half*2+w8p)*8 .. +8)
__global__ __launch_bounds__(256) void prep_kernel(
    const float* __restrict__ feat, uint8_t* __restrict__ fbT,
    float* __restrict__ sq)
{
    __shared__ __align__(16) long lt[1024];        // [chunk c 0..63][row16], swizzled
    const int t = threadIdx.x;
    const int row16 = t >> 4, seg = t & 15;
    const size_t grp = blockIdx.x;
    const size_t row = grp * 16 + row16;

    const float4* src = (const float4*)(feat + row * DIM + seg * 32);
    uint32_t wd[8];
    float s = 0.f;
#pragma unroll
    for (int i = 0; i < 4; ++i) {
        float4 a = src[2 * i], b = src[2 * i + 1];
        uint lo = (uint)__builtin_amdgcn_cvt_pk_fp8_f32(a.x, a.y, 0, false);
        lo      = (uint)__builtin_amdgcn_cvt_pk_fp8_f32(a.z, a.w, (int)lo, true);
        uint hi = (uint)__builtin_amdgcn_cvt_pk_fp8_f32(b.x, b.y, 0, false);
        hi      = (uint)__builtin_amdgcn_cvt_pk_fp8_f32(b.z, b.w, (int)hi, true);
        wd[2 * i] = lo; wd[2 * i + 1] = hi;
        s += sumsq8(lo, hi);
    }

#pragma unroll
    for (int i = 0; i < 4; ++i) {
        int c = seg * 4 + i;                       // 8B chunk of this row
        long d = ((long)(unsigned)wd[2 * i + 1] << 32) | (unsigned)wd[2 * i];
        lt[c * 16 + ((row16 + c) & 15)] = d;
    }

#pragma unroll
    for (int m = 1; m < 16; m <<= 1) s += __shfl_xor(s, m);
    if (seg == 0) sq[row] = s;

    __syncthreads();
    long* ot = (long*)(fbT + grp * 8192);
#pragma unroll
    for (int i = 0; i < 4; ++i) {
        int p    = t + i * 256;                    // output long index, coalesced
        int kk   = p >> 8;                         // 128-wide K chunk
        int rem  = p & 255;
        int half = rem >> 7;                       // lo/hi 16B of the lane's 32B
        int l6   = (rem >> 1) & 63;                // dest lane
        int qq   = l6 >> 4;                        // 32-elem scale block
        int r    = l6 & 15;                        // j row in group
        int w8   = half * 2 + (p & 1);             // 8B word within lane's 32B
        int c    = kk * 16 + qq * 4 + w8;          // source 8B chunk in row
        ot[p] = lt[c * 16 + ((r + c) & 15)];
    }
}

// ---------- entropy: symmetry-halved (R7 skeleton, measured best) + SPG=4.
// One block per unordered super-pair (a<=b) per batch: 136x4 = 544 blocks.
// i-side row-sums (rows in a -> slot b) and j-side column-sums (rows in b ->
// slot a); slot bijection => every [slot][row] written exactly once,
// atomic-free, no init. ONLY change vs R7: SPG 2->4 — half the fence points
// per group (R4->R5 measured this direction at ~+5%). LDS 2x32KB buf + 9KB
// side = 73KB -> still 2 blocks/CU. Ledger: stage_sp = 8 loads; prologue 16
// outstanding; phase sp waits vmcnt(8) (retires its own superphase, FIFO-
// oldest) except last phase vmcnt(0); stage(sp+2) issued after the seal
// barrier into the just-drained buffer.
__global__ __launch_bounds__(256, 2) void entropy_kernel(
    const uint8_t* __restrict__ fbT,
    const float* __restrict__ sq, const float* __restrict__ temp,
    float* __restrict__ Sp, float* __restrict__ Tp)
{
    __shared__ uint4 buf[2][2048];                 // 2 x 32KB (4 groups x 8KB)
    __shared__ float sqlds[256];                   // j-slice sq (1KB)
    __shared__ float sjS[4][256];                  // per-wave j-side partials (4KB)
    __shared__ float sjT[4][256];                  // (4KB)
    const int t    = threadIdx.x;
    const int w    = t >> 6;
    const int lane = t & 63;
    const int q    = lane >> 4;
    const int c16  = lane & 15;
    const int lbo  = lane * 16;

    // decode (batch, pair) -> (a, b) with a <= b
    const int flat  = blockIdx.x;
    const int batch = flat / NPAIR;
    int rem = flat - batch * NPAIR;
    int aa = 0;
    while (rem >= NSUP - aa) { rem -= NSUP - aa; ++aa; }
    const int bb = aa + rem;
    const int iw    = aa * IPB + w * IPW;
    const int jbase = bb * IPB;
    const size_t rowbase = (size_t)batch * N_TOK;

    const float tau    = temp[0];
    const float inv2t2 = 0.5f / (tau * tau);
    const float cg_    = 1.0f / (tau * tau);

    // zero this wave's j-side slots (own-wave use only until final sync)
#pragma unroll
    for (int i = 0; i < 4; ++i) { sjS[w][lane * 4 + i] = 0.f; sjT[w][lane * 4 + i] = 0.f; }

    // A fragments from fbT (A/B per-lane layouts identical for 16x16x128)
    i32x8 afrag[4][4];
#pragma unroll
    for (int s = 0; s < 4; ++s) {
        const uint8_t* ga = fbT + ((rowbase + iw) / 16 + s) * 8192;
#pragma unroll
        for (int kk = 0; kk < 4; ++kk) {
            uint4 lo = *(const uint4*)(ga + kk * 2048 + lbo);
            uint4 hi = *(const uint4*)(ga + kk * 2048 + 1024 + lbo);
            i32x8 v = {(int)lo.x, (int)lo.y, (int)lo.z, (int)lo.w,
                       (int)hi.x, (int)hi.y, (int)hi.z, (int)hi.w};
            afrag[s][kk] = v;
        }
    }
    float pi_[4][4];
    float pim = -1e30f;                            // max_i pi, for the early-out
#pragma unroll
    for (int s = 0; s < 4; ++s) {
        float4 p4 = *(const float4*)(sq + rowbase + iw + s * 16 + q * 4);
        pi_[s][0] = -p4.x * inv2t2; pi_[s][1] = -p4.y * inv2t2;
        pi_[s][2] = -p4.z * inv2t2; pi_[s][3] = -p4.w * inv2t2;
        pim = fmaxf(pim, fmaxf(fmaxf(pi_[s][0], pi_[s][1]),
                               fmaxf(pi_[s][2], pi_[s][3])));
    }
    // preload the j-super's sq values into LDS (256 floats)
    sqlds[t] = sq[rowbase + jbase + t];

    float S[4][4], T[4][4];
#pragma unroll
    for (int s = 0; s < 4; ++s)
#pragma unroll
        for (int r = 0; r < 4; ++r) { S[s][r] = 0.f; T[s][r] = 0.f; }

    const uint8_t* bgbase = fbT
        + ((size_t)batch * (N_TOK / 16) + (size_t)(jbase / 16)) * 8192;

    auto stage_sp = [&](int sp, int b) {           // wave w: its 2KB of each group
#pragma unroll
        for (int i = 0; i < SPG; ++i) {
            const uint8_t* gs = bgbase + ((size_t)sp * SPG + i) * 8192 + w * 2048 + lbo;
            uint8_t* ld = (uint8_t*)(&buf[b][0]) + i * 8192 + w * 2048;
            __builtin_amdgcn_global_load_lds((gptr_t)(const void*)gs,
                                             (lptr_t)(void*)ld, 16, 0, 0);
            __builtin_amdgcn_global_load_lds((gptr_t)(const void*)(gs + 1024),
                                             (lptr_t)(void*)(ld + 1024), 16, 0, 0);
        }
    };

    stage_sp(0, 0);
    stage_sp(1, 1);
    // one-time: sqlds/sj zeros visible to all waves (raw barrier keeps ledger)
    asm volatile("s_waitcnt lgkmcnt(0)" ::: "memory");
    __builtin_amdgcn_s_barrier();

    for (int sp = 0; sp < NSP; ++sp) {
        if (sp < NSP - 1) asm volatile("s_waitcnt vmcnt(8)" ::: "memory");
        else              asm volatile("s_waitcnt vmcnt(0)" ::: "memory");
        __builtin_amdgcn_s_barrier();              // all waves' stage(sp) confirmed
        __builtin_amdgcn_sched_barrier(0);

        const uint8_t* sb = (const uint8_t*)(&buf[sp & 1][0]);
        __builtin_amdgcn_s_setprio(1);
#pragma unroll
        for (int i = 0; i < SPG; ++i) {            // un-fenced 4-group body
            const int g = sp * SPG + i;
            const uint8_t* bs = sb + i * 8192;
            float pj = -sqlds[g * 16 + c16] * inv2t2;
            f32x4 acc[4] = {{0,0,0,0},{0,0,0,0},{0,0,0,0},{0,0,0,0}};
#pragma unroll
            for (int kk = 0; kk < 4; ++kk) {
                uint4 lo = *(const uint4*)(bs + kk * 2048 + lbo);
                uint4 hi = *(const uint4*)(bs + kk * 2048 + 1024 + lbo);
                i32x8 b = {(int)lo.x, (int)lo.y, (int)lo.z, (int)lo.w,
                           (int)hi.x, (int)hi.y, (int)hi.z, (int)hi.w};
                acc[0] = __builtin_amdgcn_mfma_scale_f32_16x16x128_f8f6f4(afrag[0][kk], b, acc[0], 0, 0, 0, 127, 0, 127);
                acc[1] = __builtin_amdgcn_mfma_scale_f32_16x16x128_f8f6f4(afrag[1][kk], b, acc[1], 0, 0, 0, 127, 0, 127);
                acc[2] = __builtin_amdgcn_mfma_scale_f32_16x16x128_f8f6f4(afrag[2][kk], b, acc[2], 0, 0, 0, 127, 0, 127);
                acc[3] = __builtin_amdgcn_mfma_scale_f32_16x16x128_f8f6f4(afrag[3][kk], b, acc[3], 0, 0, 0, 127, 0, 127);
            }
            // wave-uniform early-out (j-side shfl must be non-divergent).
            // Skipped groups' k = exp(<=-110) == 0.0f exactly -> bit-identical,
            // and their sj slots keep the pre-zeroed 0.0f.
            float m0 = fmaxf(fmaxf(acc[0][0], acc[0][1]), fmaxf(acc[0][2], acc[0][3]));
            float m1 = fmaxf(fmaxf(acc[1][0], acc[1][1]), fmaxf(acc[1][2], acc[1][3]));
            float m2 = fmaxf(fmaxf(acc[2][0], acc[2][1]), fmaxf(acc[2][2], acc[2][3]));
            float m3 = fmaxf(fmaxf(acc[3][0], acc[3][1]), fmaxf(acc[3][2], acc[3][3]));
            float mm = fmaxf(fmaxf(m0, m1), fmaxf(m2, m3));
            float bound = fmaf(mm, cg_, pim + pj);
            if (__any(bound > -110.0f)) {
                float ks = 0.f, kt = 0.f;
#pragma unroll
                for (int s = 0; s < 4; ++s)
#pragma unroll
                    for (int r = 0; r < 4; ++r) {
                        float e   = fmaf(acc[s][r], cg_, pi_[s][r] + pj);
                        float ee  = fminf(e, 0.f);
                        float k   = __expf(ee);
                        float kei = k * ee;
                        S[s][r] += k;  T[s][r] += kei;
                        ks      += k;  kt      += kei;
                    }
                if (aa != bb) {                    // j-side: reduce over the wave's 64 i
                    ks += __shfl_xor(ks, 16); ks += __shfl_xor(ks, 32);
                    kt += __shfl_xor(kt, 16); kt += __shfl_xor(kt, 32);
                    if (lane < 16) {
                        sjS[w][g * 16 + lane] = ks;
                        sjT[w][g * 16 + lane] = kt;
                    }
                }
            }
        }
        __builtin_amdgcn_s_setprio(0);

        // seal own ds_reads of buf[sp&1]; barrier -> ALL waves sealed -> safe to
        // DMA-overwrite with superphase sp+2.
        asm volatile("s_waitcnt lgkmcnt(0)" ::: "memory");
        __builtin_amdgcn_s_barrier();
        __builtin_amdgcn_sched_barrier(0);
        if (sp + 2 < NSP) stage_sp(sp + 2, sp & 1);
    }

    // ---- i-side: reduce over the 16 j-columns (c16 lanes), write slot bb ----
#pragma unroll
    for (int m = 1; m < 16; m <<= 1)
#pragma unroll
        for (int s = 0; s < 4; ++s)
#pragma unroll
            for (int r = 0; r < 4; ++r) {
                S[s][r] += __shfl_xor(S[s][r], m);
                T[s][r] += __shfl_xor(T[s][r], m);
            }
    if (c16 == 0) {
#pragma unroll
        for (int s = 0; s < 4; ++s)
#pragma unroll
            for (int r = 0; r < 4; ++r) {
                size_t idx = (size_t)bb * BN + rowbase + iw + s * 16 + q * 4 + r;
                Sp[idx] = S[s][r];
                Tp[idx] = T[s][r];
            }
    }

    // ---- j-side: combine the 4 waves' partials, write slot aa (rows in b) ----
    if (aa != bb) {
        __syncthreads();                           // all waves' sj writes visible
        float s4 = sjS[0][t] + sjS[1][t] + sjS[2][t] + sjS[3][t];
        float t4 = sjT[0][t] + sjT[1][t] + sjT[2][t] + sjT[3][t];
        size_t idx = (size_t)aa * BN + rowbase + jbase + t;
        Sp[idx] = s4;
        Tp[idx] = t4;
    }
}

// ---------- finalize: combine 16 partial slots, entropy -> sigmoid -> scale ----------
__global__ __launch_bounds__(256) void finalize_kernel(
    const float* __restrict__ feat, const float* __restrict__ Sp,
    const float* __restrict__ Tp, const float* __restrict__ tgt,
    const float* __restrict__ temp, float* __restrict__ out)
{
    int row  = (blockIdx.x << 2) + (threadIdx.x >> 6);   // global row 0..BN-1
    int lane = threadIdx.x & 63;
    float S = 0.0f, T = 0.0f;
#pragma unroll
    for (int j = 0; j < NSUP; ++j) {
        S += Sp[(size_t)j * BN + row];
        T += Tp[(size_t)j * BN + row];
    }
    float tau = temp[0];
    float E  = __logf(S) - T / S;                  // entropy (sans +1e-6, bias<4e-3)
    float cs = 1.0f / (1.0f + __expf((E - tgt[0]) / tau));

    const float4* F4 = (const float4*)(feat + (size_t)row * DIM);
    float4*       O4 = (float4*)(out + (size_t)row * DIM);
    float4 v0 = F4[lane], v1 = F4[lane + 64];
    v0.x *= cs; v0.y *= cs; v0.z *= cs; v0.w *= cs;
    v1.x *= cs; v1.y *= cs; v1.z *= cs; v1.w *= cs;
    O4[lane] = v0; O4[lane + 64] = v1;
    if (lane == 0) out[(size_t)BN * DIM + row] = cs;
}

extern "C" void kernel_launch(void* const* d_in, const int* in_sizes, int n_in,
                              void* d_out, int out_size, void* d_ws, size_t ws_size,
                              hipStream_t stream) {
    const float* feat = (const float*)d_in[0];
    const float* tgt  = (const float*)d_in[7];   // target_entropy
    const float* temp = (const float*)d_in[8];   // temperature
    float* out = (float*)d_out;

    char* ws = (char*)d_ws;
    uint8_t* fbT = (uint8_t*)ws;                               // fp8 operand-image, 8.4MB
    float*   sq  = (float*)(fbT + (size_t)BN * DIM);           // quantized row sumsq
    float*   Sp  = sq + BN;                                    // partial S, NSUP slots
    float*   Tp  = Sp + (size_t)NSUP * BN;                     // partial T, NSUP slots

    prep_kernel<<<dim3(BN / 16), dim3(256), 0, stream>>>(feat, fbT, sq);
    entropy_kernel<<<dim3(BATCH * NPAIR), dim3(256), 0, stream>>>(fbT, sq, temp, Sp, Tp);
    finalize_kernel<<<dim3(BN / 4), dim3(256), 0, stream>>>(feat, Sp, Tp, tgt, temp, out);
}

// Round 11
// 138.608 us; speedup vs baseline: 1.0705x; 1.0064x over previous
//
#include <hip/hip_runtime.h>
#include <stdint.h>

#define N_TOK 4096
#define DIM   512
#define BATCH 4
#define BN    (BATCH * N_TOK)
#define NSUP  16                      // 256-row super-tiles per batch
#define NPAIR 136                     // NSUP*(NSUP+1)/2 unordered pairs
#define IPW   64                      // i-rows per wave (A resident in regs)
#define IPB   256                     // i-rows per block (4 waves) = one super-tile
#define NG2   16                      // j-groups of 16 per super-tile
#define SPG   4                       // j-groups per superphase (un-fenced body)
#define NSP   (NG2 / SPG)             // 4 superphases

typedef __attribute__((ext_vector_type(4))) float f32x4;
typedef __attribute__((ext_vector_type(8))) int   i32x8;

typedef const __attribute__((address_space(1))) uint32_t* gptr_t;
typedef __attribute__((address_space(3))) uint32_t* lptr_t;

__device__ __forceinline__ float sumsq8(uint lo, uint hi) {
    float s = 0.f, f;
    f = __builtin_amdgcn_cvt_f32_fp8((int)lo, 0); s = fmaf(f, f, s);
    f = __builtin_amdgcn_cvt_f32_fp8((int)lo, 1); s = fmaf(f, f, s);
    f = __builtin_amdgcn_cvt_f32_fp8((int)lo, 2); s = fmaf(f, f, s);
    f = __builtin_amdgcn_cvt_f32_fp8((int)lo, 3); s = fmaf(f, f, s);
    f = __builtin_amdgcn_cvt_f32_fp8((int)hi, 0); s = fmaf(f, f, s);
    f = __builtin_amdgcn_cvt_f32_fp8((int)hi, 1); s = fmaf(f, f, s);
    f = __builtin_amdgcn_cvt_f32_fp8((int)hi, 2); s = fmaf(f, f, s);
    f = __builtin_amdgcn_cvt_f32_fp8((int)hi, 3); s = fmaf(f, f, s);
    return s;
}

// ---------- prep: fp8 convert -> fbT (operand-image layout) + per-row sumsq of
// QUANTIZED values over the FULL 512 dims (sq) AND over the first 256 dims
// (sq2, for the mid-K prune bound). fbT per 16-row group (8KB):
//   byte = kk*2048 + half*1024 + lane*16 + w8p*8, lane = q*16 + r
//   content = row r, K bytes [kk*128 + q*32 + (half*2+w8p)*8 .. +8)
__global__ __launch_bounds__(256) void prep_kernel(
    const float* __restrict__ feat, uint8_t* __restrict__ fbT,
    float* __restrict__ sq, float* __restrict__ sq2)
{
    __shared__ __align__(16) long lt[1024];        // [chunk c 0..63][row16], swizzled
    const int t = threadIdx.x;
    const int row16 = t >> 4, seg = t & 15;
    const size_t grp = blockIdx.x;
    const size_t row = grp * 16 + row16;

    const float4* src = (const float4*)(feat + row * DIM + seg * 32);
    uint32_t wd[8];
    float s = 0.f;
#pragma unroll
    for (int i = 0; i < 4; ++i) {
        float4 a = src[2 * i], b = src[2 * i + 1];
        uint lo = (uint)__builtin_amdgcn_cvt_pk_fp8_f32(a.x, a.y, 0, false);
        lo      = (uint)__builtin_amdgcn_cvt_pk_fp8_f32(a.z, a.w, (int)lo, true);
        uint hi = (uint)__builtin_amdgcn_cvt_pk_fp8_f32(b.x, b.y, 0, false);
        hi      = (uint)__builtin_amdgcn_cvt_pk_fp8_f32(b.z, b.w, (int)hi, true);
        wd[2 * i] = lo; wd[2 * i + 1] = hi;
        s += sumsq8(lo, hi);
    }

#pragma unroll
    for (int i = 0; i < 4; ++i) {
        int c = seg * 4 + i;                       // 8B chunk of this row
        long d = ((long)(unsigned)wd[2 * i + 1] << 32) | (unsigned)wd[2 * i];
        lt[c * 16 + ((row16 + c) & 15)] = d;
    }

    float s2 = (seg < 8) ? s : 0.f;                // first 256 dims = seg 0..7
#pragma unroll
    for (int m = 1; m < 16; m <<= 1) {
        s  += __shfl_xor(s, m);
        s2 += __shfl_xor(s2, m);
    }
    if (seg == 0) { sq[row] = s; sq2[row] = s2; }

    __syncthreads();
    long* ot = (long*)(fbT + grp * 8192);
#pragma unroll
    for (int i = 0; i < 4; ++i) {
        int p    = t + i * 256;                    // output long index, coalesced
        int kk   = p >> 8;                         // 128-wide K chunk
        int rem  = p & 255;
        int half = rem >> 7;                       // lo/hi 16B of the lane's 32B
        int l6   = (rem >> 1) & 63;                // dest lane
        int qq   = l6 >> 4;                        // 32-elem scale block
        int r    = l6 & 15;                        // j row in group
        int w8   = half * 2 + (p & 1);             // 8B word within lane's 32B
        int c    = kk * 16 + qq * 4 + w8;          // source 8B chunk in row
        ot[p] = lt[c * 16 + ((r + c) & 15)];
    }
}

// ---------- entropy: symmetry-halved (R10 skeleton, measured best) + MID-K PRUNE.
// Monotonicity of quantized d2: d2_full >= d2_{K<=256}, so
//   e_full <= e_256 = acc256*cg + pi2 + pj2   (pi2/pj2 from first-256 sumsq).
// Per group: run kk=0,1 (8 MFMAs) -> conservative partial bound
// (mm256*cg + pim2 + pj2, wave-__any). Fail => e_full < -110 for every pair =>
// every exp underflows to 0.0f exactly => skip kk=2,3 AND all tails:
// bit-identical, 53% of MFMA issue + LDS reads for off-diagonal pair-blocks
// (all groups far) and 12/16 groups of diagonal blocks.
// Slot bijection, staging, and vmcnt ledger unchanged from R10: stage_sp = 8
// loads; prologue 16 outstanding; phase sp waits vmcnt(8) except last vmcnt(0);
// stage(sp+2) after the seal barrier.
__global__ __launch_bounds__(256, 2) void entropy_kernel(
    const uint8_t* __restrict__ fbT,
    const float* __restrict__ sq, const float* __restrict__ sq2,
    const float* __restrict__ temp,
    float* __restrict__ Sp, float* __restrict__ Tp)
{
    __shared__ uint4 buf[2][2048];                 // 2 x 32KB (4 groups x 8KB)
    __shared__ float sqlds[256];                   // j-slice sq (1KB)
    __shared__ float sq2lds[256];                  // j-slice sq2 (1KB)
    __shared__ float sjS[4][256];                  // per-wave j-side partials (4KB)
    __shared__ float sjT[4][256];                  // (4KB)
    const int t    = threadIdx.x;
    const int w    = t >> 6;
    const int lane = t & 63;
    const int q    = lane >> 4;
    const int c16  = lane & 15;
    const int lbo  = lane * 16;

    // decode (batch, pair) -> (a, b) with a <= b
    const int flat  = blockIdx.x;
    const int batch = flat / NPAIR;
    int rem = flat - batch * NPAIR;
    int aa = 0;
    while (rem >= NSUP - aa) { rem -= NSUP - aa; ++aa; }
    const int bb = aa + rem;
    const int iw    = aa * IPB + w * IPW;
    const int jbase = bb * IPB;
    const size_t rowbase = (size_t)batch * N_TOK;

    const float tau    = temp[0];
    const float inv2t2 = 0.5f / (tau * tau);
    const float cg_    = 1.0f / (tau * tau);

    // zero this wave's j-side slots (own-wave use only until final sync)
#pragma unroll
    for (int i = 0; i < 4; ++i) { sjS[w][lane * 4 + i] = 0.f; sjT[w][lane * 4 + i] = 0.f; }

    // A fragments from fbT (A/B per-lane layouts identical for 16x16x128)
    i32x8 afrag[4][4];
#pragma unroll
    for (int s = 0; s < 4; ++s) {
        const uint8_t* ga = fbT + ((rowbase + iw) / 16 + s) * 8192;
#pragma unroll
        for (int kk = 0; kk < 4; ++kk) {
            uint4 lo = *(const uint4*)(ga + kk * 2048 + lbo);
            uint4 hi = *(const uint4*)(ga + kk * 2048 + 1024 + lbo);
            i32x8 v = {(int)lo.x, (int)lo.y, (int)lo.z, (int)lo.w,
                       (int)hi.x, (int)hi.y, (int)hi.z, (int)hi.w};
            afrag[s][kk] = v;
        }
    }
    float pi_[4][4];
    float pim  = -1e30f;                           // max_i pi, full-K early-out
    float mn2  =  1e30f;                           // min_i sq2 -> pim2
#pragma unroll
    for (int s = 0; s < 4; ++s) {
        float4 p4 = *(const float4*)(sq + rowbase + iw + s * 16 + q * 4);
        pi_[s][0] = -p4.x * inv2t2; pi_[s][1] = -p4.y * inv2t2;
        pi_[s][2] = -p4.z * inv2t2; pi_[s][3] = -p4.w * inv2t2;
        pim = fmaxf(pim, fmaxf(fmaxf(pi_[s][0], pi_[s][1]),
                               fmaxf(pi_[s][2], pi_[s][3])));
        float4 r4 = *(const float4*)(sq2 + rowbase + iw + s * 16 + q * 4);
        mn2 = fminf(mn2, fminf(fminf(r4.x, r4.y), fminf(r4.z, r4.w)));
    }
    const float pim2 = -mn2 * inv2t2;              // max_i pi2 (lane's 16 i-rows)
    // preload the j-super's sq/sq2 values into LDS (256 floats each)
    sqlds[t]  = sq[rowbase + jbase + t];
    sq2lds[t] = sq2[rowbase + jbase + t];

    float S[4][4], T[4][4];
#pragma unroll
    for (int s = 0; s < 4; ++s)
#pragma unroll
        for (int r = 0; r < 4; ++r) { S[s][r] = 0.f; T[s][r] = 0.f; }

    const uint8_t* bgbase = fbT
        + ((size_t)batch * (N_TOK / 16) + (size_t)(jbase / 16)) * 8192;

    auto stage_sp = [&](int sp, int b) {           // wave w: its 2KB of each group
#pragma unroll
        for (int i = 0; i < SPG; ++i) {
            const uint8_t* gs = bgbase + ((size_t)sp * SPG + i) * 8192 + w * 2048 + lbo;
            uint8_t* ld = (uint8_t*)(&buf[b][0]) + i * 8192 + w * 2048;
            __builtin_amdgcn_global_load_lds((gptr_t)(const void*)gs,
                                             (lptr_t)(void*)ld, 16, 0, 0);
            __builtin_amdgcn_global_load_lds((gptr_t)(const void*)(gs + 1024),
                                             (lptr_t)(void*)(ld + 1024), 16, 0, 0);
        }
    };

    stage_sp(0, 0);
    stage_sp(1, 1);
    // one-time: sqlds/sq2lds/sj zeros visible to all waves (raw barrier keeps ledger)
    asm volatile("s_waitcnt lgkmcnt(0)" ::: "memory");
    __builtin_amdgcn_s_barrier();

    for (int sp = 0; sp < NSP; ++sp) {
        if (sp < NSP - 1) asm volatile("s_waitcnt vmcnt(8)" ::: "memory");
        else              asm volatile("s_waitcnt vmcnt(0)" ::: "memory");
        __builtin_amdgcn_s_barrier();              // all waves' stage(sp) confirmed
        __builtin_amdgcn_sched_barrier(0);

        const uint8_t* sb = (const uint8_t*)(&buf[sp & 1][0]);
        __builtin_amdgcn_s_setprio(1);
#pragma unroll
        for (int i = 0; i < SPG; ++i) {            // un-fenced 4-group body
            const int g = sp * SPG + i;
            const uint8_t* bs = sb + i * 8192;
            float pj  = -sqlds[g * 16 + c16]  * inv2t2;
            float pj2 = -sq2lds[g * 16 + c16] * inv2t2;
            f32x4 acc[4] = {{0,0,0,0},{0,0,0,0},{0,0,0,0},{0,0,0,0}};
#pragma unroll
            for (int kk = 0; kk < 2; ++kk) {       // first half of K
                uint4 lo = *(const uint4*)(bs + kk * 2048 + lbo);
                uint4 hi = *(const uint4*)(bs + kk * 2048 + 1024 + lbo);
                i32x8 b = {(int)lo.x, (int)lo.y, (int)lo.z, (int)lo.w,
                           (int)hi.x, (int)hi.y, (int)hi.z, (int)hi.w};
                acc[0] = __builtin_amdgcn_mfma_scale_f32_16x16x128_f8f6f4(afrag[0][kk], b, acc[0], 0, 0, 0, 127, 0, 127);
                acc[1] = __builtin_amdgcn_mfma_scale_f32_16x16x128_f8f6f4(afrag[1][kk], b, acc[1], 0, 0, 0, 127, 0, 127);
                acc[2] = __builtin_amdgcn_mfma_scale_f32_16x16x128_f8f6f4(afrag[2][kk], b, acc[2], 0, 0, 0, 127, 0, 127);
                acc[3] = __builtin_amdgcn_mfma_scale_f32_16x16x128_f8f6f4(afrag[3][kk], b, acc[3], 0, 0, 0, 127, 0, 127);
            }
            // mid-K prune: e_full <= acc256*cg + pi2 + pj2 (monotone d2). If the
            // whole wave's bound < -110, every exp underflows to 0.0f exactly.
            float n0 = fmaxf(fmaxf(acc[0][0], acc[0][1]), fmaxf(acc[0][2], acc[0][3]));
            float n1 = fmaxf(fmaxf(acc[1][0], acc[1][1]), fmaxf(acc[1][2], acc[1][3]));
            float n2 = fmaxf(fmaxf(acc[2][0], acc[2][1]), fmaxf(acc[2][2], acc[2][3]));
            float n3 = fmaxf(fmaxf(acc[3][0], acc[3][1]), fmaxf(acc[3][2], acc[3][3]));
            float nn = fmaxf(fmaxf(n0, n1), fmaxf(n2, n3));
            if (__any(fmaf(nn, cg_, pim2 + pj2) > -110.0f)) {
#pragma unroll
                for (int kk = 2; kk < 4; ++kk) {   // second half of K
                    uint4 lo = *(const uint4*)(bs + kk * 2048 + lbo);
                    uint4 hi = *(const uint4*)(bs + kk * 2048 + 1024 + lbo);
                    i32x8 b = {(int)lo.x, (int)lo.y, (int)lo.z, (int)lo.w,
                               (int)hi.x, (int)hi.y, (int)hi.z, (int)hi.w};
                    acc[0] = __builtin_amdgcn_mfma_scale_f32_16x16x128_f8f6f4(afrag[0][kk], b, acc[0], 0, 0, 0, 127, 0, 127);
                    acc[1] = __builtin_amdgcn_mfma_scale_f32_16x16x128_f8f6f4(afrag[1][kk], b, acc[1], 0, 0, 0, 127, 0, 127);
                    acc[2] = __builtin_amdgcn_mfma_scale_f32_16x16x128_f8f6f4(afrag[2][kk], b, acc[2], 0, 0, 0, 127, 0, 127);
                    acc[3] = __builtin_amdgcn_mfma_scale_f32_16x16x128_f8f6f4(afrag[3][kk], b, acc[3], 0, 0, 0, 127, 0, 127);
                }
                // full-K early-out (as before); skipped -> exact 0.0f contributions
                float m0 = fmaxf(fmaxf(acc[0][0], acc[0][1]), fmaxf(acc[0][2], acc[0][3]));
                float m1 = fmaxf(fmaxf(acc[1][0], acc[1][1]), fmaxf(acc[1][2], acc[1][3]));
                float m2 = fmaxf(fmaxf(acc[2][0], acc[2][1]), fmaxf(acc[2][2], acc[2][3]));
                float m3 = fmaxf(fmaxf(acc[3][0], acc[3][1]), fmaxf(acc[3][2], acc[3][3]));
                float mm = fmaxf(fmaxf(m0, m1), fmaxf(m2, m3));
                float bound = fmaf(mm, cg_, pim + pj);
                if (__any(bound > -110.0f)) {
                    float ks = 0.f, kt = 0.f;
#pragma unroll
                    for (int s = 0; s < 4; ++s)
#pragma unroll
                        for (int r = 0; r < 4; ++r) {
                            float e   = fmaf(acc[s][r], cg_, pi_[s][r] + pj);
                            float ee  = fminf(e, 0.f);
                            float k   = __expf(ee);
                            float kei = k * ee;
                            S[s][r] += k;  T[s][r] += kei;
                            ks      += k;  kt      += kei;
                        }
                    if (aa != bb) {                // j-side: reduce over the wave's 64 i
                        ks += __shfl_xor(ks, 16); ks += __shfl_xor(ks, 32);
                        kt += __shfl_xor(kt, 16); kt += __shfl_xor(kt, 32);
                        if (lane < 16) {
                            sjS[w][g * 16 + lane] = ks;
                            sjT[w][g * 16 + lane] = kt;
                        }
                    }
                }
            }
        }
        __builtin_amdgcn_s_setprio(0);

        // seal own ds_reads of buf[sp&1]; barrier -> ALL waves sealed -> safe to
        // DMA-overwrite with superphase sp+2.
        asm volatile("s_waitcnt lgkmcnt(0)" ::: "memory");
        __builtin_amdgcn_s_barrier();
        __builtin_amdgcn_sched_barrier(0);
        if (sp + 2 < NSP) stage_sp(sp + 2, sp & 1);
    }

    // ---- i-side: reduce over the 16 j-columns (c16 lanes), write slot bb ----
#pragma unroll
    for (int m = 1; m < 16; m <<= 1)
#pragma unroll
        for (int s = 0; s < 4; ++s)
#pragma unroll
            for (int r = 0; r < 4; ++r) {
                S[s][r] += __shfl_xor(S[s][r], m);
                T[s][r] += __shfl_xor(T[s][r], m);
            }
    if (c16 == 0) {
#pragma unroll
        for (int s = 0; s < 4; ++s)
#pragma unroll
            for (int r = 0; r < 4; ++r) {
                size_t idx = (size_t)bb * BN + rowbase + iw + s * 16 + q * 4 + r;
                Sp[idx] = S[s][r];
                Tp[idx] = T[s][r];
            }
    }

    // ---- j-side: combine the 4 waves' partials, write slot aa (rows in b) ----
    if (aa != bb) {
        __syncthreads();                           // all waves' sj writes visible
        float s4 = sjS[0][t] + sjS[1][t] + sjS[2][t] + sjS[3][t];
        float t4 = sjT[0][t] + sjT[1][t] + sjT[2][t] + sjT[3][t];
        size_t idx = (size_t)aa * BN + rowbase + jbase + t;
        Sp[idx] = s4;
        Tp[idx] = t4;
    }
}

// ---------- finalize: combine 16 partial slots, entropy -> sigmoid -> scale ----------
__global__ __launch_bounds__(256) void finalize_kernel(
    const float* __restrict__ feat, const float* __restrict__ Sp,
    const float* __restrict__ Tp, const float* __restrict__ tgt,
    const float* __restrict__ temp, float* __restrict__ out)
{
    int row  = (blockIdx.x << 2) + (threadIdx.x >> 6);   // global row 0..BN-1
    int lane = threadIdx.x & 63;
    float S = 0.0f, T = 0.0f;
#pragma unroll
    for (int j = 0; j < NSUP; ++j) {
        S += Sp[(size_t)j * BN + row];
        T += Tp[(size_t)j * BN + row];
    }
    float tau = temp[0];
    float E  = __logf(S) - T / S;                  // entropy (sans +1e-6, bias<4e-3)
    float cs = 1.0f / (1.0f + __expf((E - tgt[0]) / tau));

    const float4* F4 = (const float4*)(feat + (size_t)row * DIM);
    float4*       O4 = (float4*)(out + (size_t)row * DIM);
    float4 v0 = F4[lane], v1 = F4[lane + 64];
    v0.x *= cs; v0.y *= cs; v0.z *= cs; v0.w *= cs;
    v1.x *= cs; v1.y *= cs; v1.z *= cs; v1.w *= cs;
    O4[lane] = v0; O4[lane + 64] = v1;
    if (lane == 0) out[(size_t)BN * DIM + row] = cs;
}

extern "C" void kernel_launch(void* const* d_in, const int* in_sizes, int n_in,
                              void* d_out, int out_size, void* d_ws, size_t ws_size,
                              hipStream_t stream) {
    const float* feat = (const float*)d_in[0];
    const float* tgt  = (const float*)d_in[7];   // target_entropy
    const float* temp = (const float*)d_in[8];   // temperature
    float* out = (float*)d_out;

    char* ws = (char*)d_ws;
    uint8_t* fbT = (uint8_t*)ws;                               // fp8 operand-image, 8.4MB
    float*   sq  = (float*)(fbT + (size_t)BN * DIM);           // quantized row sumsq (full K)
    float*   sq2 = sq + BN;                                    // quantized row sumsq (K<256)
    float*   Sp  = sq2 + BN;                                   // partial S, NSUP slots
    float*   Tp  = Sp + (size_t)NSUP * BN;                     // partial T, NSUP slots

    prep_kernel<<<dim3(BN / 16), dim3(256), 0, stream>>>(feat, fbT, sq, sq2);
    entropy_kernel<<<dim3(BATCH * NPAIR), dim3(256), 0, stream>>>(fbT, sq, sq2, temp, Sp, Tp);
    finalize_kernel<<<dim3(BN / 4), dim3(256), 0, stream>>>(feat, Sp, Tp, tgt, temp, out);
}